// Round 4
// baseline (265.554 us; speedup 1.0000x reference)
//
#include <hip/hip_runtime.h>
#include <stdint.h>
#include <math.h>

#define N_NODES 20000
#define C_IN 128
#define C_OUT 64
#define T_STEPS 8
#define NE 160000
#define NB_STATS 1024
#define NB_DEG ((NE + 255) / 256)   // 625
#define NB_LIF ((N_NODES * C_IN) / 256)  // 10000
#define NPB 8        // nodes per block in main kernel
#define RPAD 264     // Bls row stride (bf16 units): 256 + 8 pad

typedef __attribute__((ext_vector_type(8))) short short8;
typedef __attribute__((ext_vector_type(4))) float f32x4;

static __device__ __forceinline__ unsigned short bf16_rne(float f) {
  unsigned u = __builtin_bit_cast(unsigned, f);
  return (unsigned short)((u + 0x7FFFu + ((u >> 16) & 1u)) >> 16);
}

// ---------------- K1: deg atomics + per-channel partial sums (fp64) + WTb build ----------------
// WTb layout: [(mt*8+kt)*64 + lane] * 8 bf16 ; A[m][k], m=mt*16+(lane&15), k=kt*32+(lane>>4)*8+j
__global__ __launch_bounds__(256) void stats_deg_wtb_kernel(const float* __restrict__ x,
                                                            double* __restrict__ dsum,
                                                            double* __restrict__ dsq,
                                                            const int* __restrict__ ei,
                                                            int* __restrict__ deg,
                                                            const float* __restrict__ W0,
                                                            const float* __restrict__ W1,
                                                            unsigned short* __restrict__ WTb) {
  int tid = threadIdx.x;
  if (blockIdx.x < NB_DEG) {                       // degree count (latency-bound, drains early)
    int e = blockIdx.x * 256 + tid;
    if (e < NE) atomicAdd(&deg[ei[NE + e]], 1);
    return;
  }
  if (blockIdx.x >= NB_DEG + NB_STATS) {           // WTb build (8 blocks)
    int idx = (blockIdx.x - NB_DEG - NB_STATS) * 256 + tid;  // 2048 threads
    int mt = idx >> 9, kt = (idx >> 6) & 7, lane = idx & 63;
    int m = mt * 16 + (lane & 15);
    int kb = kt * 32 + (lane >> 4) * 8;
    unsigned short frag[8];
#pragma unroll
    for (int j = 0; j < 8; ++j) {
      int k = kb + j;
      float wv = (k < 128) ? W0[m * 128 + k] : W1[m * 128 + (k - 128)];
      frag[j] = bf16_rne(wv);
    }
    *(uint4*)&WTb[(size_t)idx * 8] = *(uint4*)frag;
    return;
  }
  // stats partials
  int sb = blockIdx.x - NB_DEG;
  const int P = N_NODES * C_IN;
  int gid = sb * 256 + tid;
  double s = 0.0, q = 0.0;
  for (int p = gid; p < P; p += 256 * NB_STATS) {  // stride % 128 == 0 -> c constant per thread
    const float4* xp = (const float4*)(x + (size_t)p * 8);
    float4 a = xp[0], b = xp[1];
    float v[8] = {a.x, a.y, a.z, a.w, b.x, b.y, b.z, b.w};
#pragma unroll
    for (int j = 0; j < 8; ++j) { double d = (double)v[j]; s += d; q += d * d; }
  }
  __shared__ double ls[256], lq[256];
  ls[tid] = s; lq[tid] = q;
  __syncthreads();
  if (tid < 128) {  // tid and tid+128 share channel c==tid
    dsum[tid * NB_STATS + sb] = ls[tid] + ls[tid + 128];
    dsq [tid * NB_STATS + sb] = lq[tid] + lq[tid + 128];
  }
}

// ---------------- K2: finalize per-channel scale/shift + CSR scan + dinv (fused) ----------------
__global__ __launch_bounds__(256) void finalize_scan_kernel(const double* __restrict__ dsum,
                                                            const double* __restrict__ dsq,
                                                            const float* __restrict__ gamma,
                                                            const float* __restrict__ beta,
                                                            double* __restrict__ adbl,
                                                            double* __restrict__ bdbl,
                                                            const int* __restrict__ deg,
                                                            int* __restrict__ offs,
                                                            int* __restrict__ cursor,
                                                            float* __restrict__ dinv) {
  int tid = threadIdx.x;
  if (blockIdx.x == 128) {  // ---- scan block: 79 nodes/thread, two passes over L2-hot deg ----
    int lane = tid & 63, w = tid >> 6;
    int base = tid * 79;  // 256*79 = 20224 >= 20000
    int s = 0;
#pragma unroll 1
    for (int i = 0; i < 79; ++i) {
      int n = base + i;
      if (n < N_NODES) s += deg[n];
    }
    int p = s;
#pragma unroll
    for (int o = 1; o < 64; o <<= 1) {
      int u = __shfl_up(p, o);
      if (lane >= o) p += u;
    }
    __shared__ int wsum[4];
    if (lane == 63) wsum[w] = p;
    __syncthreads();
    int wpre = 0;
    for (int j = 0; j < w; ++j) wpre += wsum[j];
    int run = wpre + p - s;
#pragma unroll 1
    for (int i = 0; i < 79; ++i) {
      int n = base + i;
      if (n < N_NODES) {
        int d = deg[n];
        offs[n] = run; cursor[n] = run;
        dinv[n] = d > 0 ? (float)(1.0 / sqrt((double)d)) : 0.f;
        run += d;
      }
    }
    if (tid == 0) offs[N_NODES] = wsum[0] + wsum[1] + wsum[2] + wsum[3];
    return;
  }
  // ---- finalize block: channel c ----
  int c = blockIdx.x;
  __shared__ double ls[256], lq[256];
  double s = 0.0, q = 0.0;
#pragma unroll
  for (int i = 0; i < NB_STATS / 256; ++i) {
    s += dsum[c * NB_STATS + tid + 256 * i];
    q += dsq [c * NB_STATS + tid + 256 * i];
  }
  ls[tid] = s; lq[tid] = q;
  __syncthreads();
  for (int o = 128; o > 0; o >>= 1) {
    if (tid < o) { ls[tid] += ls[tid + o]; lq[tid] += lq[tid + o]; }
    __syncthreads();
  }
  if (tid == 0) {
    const double cnt = (double)N_NODES * T_STEPS;
    double mean = ls[0] / cnt;
    double var  = lq[0] / cnt - mean * mean;
    double ai = (double)gamma[c] / sqrt(var + 1e-5);
    adbl[c] = ai;
    bdbl[c] = (double)beta[c] - mean * ai;
  }
}

// ---------------- K3: LIF recurrence (fp64) + bit-pack spikes + CSR fill (fused) ----------------
__global__ __launch_bounds__(256) void lif_fill_kernel(const float* __restrict__ x,
                                                       const double* __restrict__ adbl,
                                                       const double* __restrict__ bdbl,
                                                       unsigned char* __restrict__ spk,
                                                       const int* __restrict__ ei,
                                                       int* __restrict__ cursor,
                                                       int* __restrict__ csr) {
  int tid = threadIdx.x;
  if (blockIdx.x >= NB_LIF) {   // CSR fill: hides under lif's HBM phase
    int e = (blockIdx.x - NB_LIF) * 256 + tid;
    if (e < NE) {
      int pos = atomicAdd(&cursor[ei[NE + e]], 1);
      csr[pos] = ei[e];
    }
    return;
  }
  int p = blockIdx.x * 256 + tid;  // exactly N*C threads
  int c = p & (C_IN - 1);
  const float4* xp = (const float4*)(x + (size_t)p * 8);
  float4 a4 = xp[0], b4 = xp[1];
  float v[8] = {a4.x, a4.y, a4.z, a4.w, b4.x, b4.y, b4.z, b4.w};
  double a = adbl[c], bb = bdbl[c];
  double mem = 0.0, sp = 0.0;
  unsigned byte = 0;
#pragma unroll
  for (int t = 0; t < 8; ++t) {
    double h = a * (double)v[t] + bb;
    mem = mem * (0.2 * (1.0 - sp)) + h;
    int fire = mem > 0.5;
    sp = fire ? 1.0 : 0.0;
    byte |= (unsigned)fire << t;
  }
  spk[p] = (unsigned char)byte;
}

// ---------------- K4: fused spike expand + edge aggregate + MFMA GEMM + bias ----------------
// 512 threads = 8 waves; 8 nodes/block, 1 node per wave in Phase B.
__global__ __launch_bounds__(512) void main_kernel(const unsigned char* __restrict__ spk,
                                                   const int* __restrict__ offs,
                                                   const int* __restrict__ csr,
                                                   const float* __restrict__ dinv,
                                                   const unsigned short* __restrict__ WTb,
                                                   const float* __restrict__ bias,
                                                   float* __restrict__ out) {
  __shared__ unsigned short Bls[64 * RPAD];  // [col][k] bf16, col=nl*8+t, k=0..255
  int tid = threadIdx.x;
  int n0 = blockIdx.x * NPB;
  int lane = tid & 63, w = tid >> 6;

  // Phase A: expand own spikes into k in [0,128). 512 tasks = 64 cols x 8 channel-groups.
  {
    int col = tid & 63, cg = tid >> 6;
    int node = n0 + (col >> 3), t = col & 7;
    uint4 u = *(const uint4*)(spk + (size_t)node * 128 + cg * 16);
    unsigned ua[4] = {u.x, u.y, u.z, u.w};
    unsigned ow[8];
#pragma unroll
    for (int i = 0; i < 4; ++i) {
      unsigned vv = (ua[i] >> t) & 0x01010101u;
      unsigned s0 = (vv & 1u)         ? 0x3F80u : 0u;
      unsigned s1 = ((vv >> 8) & 1u)  ? 0x3F800000u : 0u;
      unsigned s2 = ((vv >> 16) & 1u) ? 0x3F80u : 0u;
      unsigned s3 = (vv >> 24)        ? 0x3F800000u : 0u;
      ow[i * 2]     = s0 | s1;
      ow[i * 2 + 1] = s2 | s3;
    }
    uint4 o0 = {ow[0], ow[1], ow[2], ow[3]};
    uint4 o1 = {ow[4], ow[5], ow[6], ow[7]};
    *(uint4*)&Bls[col * RPAD + cg * 16]     = o0;
    *(uint4*)&Bls[col * RPAD + cg * 16 + 8] = o1;
  }

  // Phase B: wave w aggregates node n0+w; lane covers channels 2*lane, 2*lane+1.
  {
    int node = n0 + w;
    int e0 = offs[node], e1 = offs[node + 1];
    const unsigned short* sp16 = (const unsigned short*)spk;
    float acc[16];
#pragma unroll
    for (int j = 0; j < 16; ++j) acc[j] = 0.f;
    int e = e0;
#pragma unroll 1
    for (; e + 4 <= e1; e += 4) {  // 4 edges in flight -> latency chain /4
      int s0 = csr[e], s1 = csr[e + 1], s2 = csr[e + 2], s3 = csr[e + 3];
      float w0 = dinv[s0], w1 = dinv[s1], w2 = dinv[s2], w3 = dinv[s3];
      unsigned b0 = sp16[(size_t)s0 * 64 + lane];
      unsigned b1 = sp16[(size_t)s1 * 64 + lane];
      unsigned b2 = sp16[(size_t)s2 * 64 + lane];
      unsigned b3 = sp16[(size_t)s3 * 64 + lane];
#pragma unroll
      for (int j = 0; j < 16; ++j) {
        acc[j] = fmaf((float)((b0 >> j) & 1u), w0, acc[j]);
        acc[j] = fmaf((float)((b1 >> j) & 1u), w1, acc[j]);
        acc[j] = fmaf((float)((b2 >> j) & 1u), w2, acc[j]);
        acc[j] = fmaf((float)((b3 >> j) & 1u), w3, acc[j]);
      }
    }
#pragma unroll 1
    for (; e < e1; ++e) {
      int src = csr[e];
      float wt = dinv[src];
      unsigned bits = sp16[(size_t)src * 64 + lane];
#pragma unroll
      for (int j = 0; j < 16; ++j)
        acc[j] = fmaf((float)((bits >> j) & 1u), wt, acc[j]);
    }
    float sc = dinv[node];
    int colb = w * 8;
    int c0 = 2 * lane;
#pragma unroll
    for (int t = 0; t < 8; ++t) {
      unsigned pk = (unsigned)bf16_rne(acc[t] * sc) |
                    ((unsigned)bf16_rne(acc[8 + t] * sc) << 16);
      *(unsigned*)&Bls[(colb + t) * RPAD + 128 + c0] = pk;
    }
  }
  __syncthreads();

  // Phase C: D[m=d][n=col] = sum_k WT[m][k] * B[k][n] via 16x16x32 bf16 MFMA.
  // 16 tiles (mt 0..3 x ct 0..3); wave w does (mt=w&3, ct=w>>2) and (mt=w&3, ct=(w>>2)+2).
  int q = lane >> 4, l16 = lane & 15;
  int mt = w & 3, ct0 = w >> 2, ct1 = ct0 + 2;
  int colA = ct0 * 16 + l16, colB = ct1 * 16 + l16;
  const short8* WT8 = (const short8*)WTb;
  f32x4 acc0 = {0, 0, 0, 0}, acc1 = {0, 0, 0, 0};
#pragma unroll
  for (int kt = 0; kt < 8; ++kt) {
    short8 a = WT8[(mt * 8 + kt) * 64 + lane];
    short8 bA = *(const short8*)&Bls[colA * RPAD + kt * 32 + q * 8];
    short8 bB = *(const short8*)&Bls[colB * RPAD + kt * 32 + q * 8];
    acc0 = __builtin_amdgcn_mfma_f32_16x16x32_bf16(a, bA, acc0, 0, 0, 0);
    acc1 = __builtin_amdgcn_mfma_f32_16x16x32_bf16(a, bB, acc1, 0, 0, 0);
  }

  // Epilogue: C/D layout col=lane&15, row=(lane>>4)*4+reg
  int nodeA = n0 + (colA >> 3), tA = colA & 7;
  int nodeB = n0 + (colB >> 3), tB = colB & 7;
  float* obA = out + (size_t)nodeA * 512 + tA;
  float* obB = out + (size_t)nodeB * 512 + tB;
#pragma unroll
  for (int r = 0; r < 4; ++r) {
    int d = mt * 16 + q * 4 + r;
    float bv = bias[d];
    obA[d * 8] = acc0[r] + bv;
    obB[d * 8] = acc1[r] + bv;
  }
}

extern "C" void kernel_launch(void* const* d_in, const int* in_sizes, int n_in,
                              void* d_out, int out_size, void* d_ws, size_t ws_size,
                              hipStream_t stream) {
  const float* x     = (const float*)d_in[0];
  const int*   ei    = (const int*)d_in[1];
  const float* gamma = (const float*)d_in[2];
  const float* beta  = (const float*)d_in[3];
  const float* W0    = (const float*)d_in[4];
  const float* W1    = (const float*)d_in[5];
  const float* bias  = (const float*)d_in[6];
  float* out = (float*)d_out;

  char* ws = (char*)d_ws;
  size_t off = 0;
  auto alloc = [&](size_t bytes) -> void* {
    void* p = ws + off;
    off = (off + bytes + 255) & ~(size_t)255;
    return p;
  };
  double* dsum = (double*)alloc(128 * NB_STATS * 8);
  double* dsq  = (double*)alloc(128 * NB_STATS * 8);
  double* adbl = (double*)alloc(128 * 8);
  double* bdbl = (double*)alloc(128 * 8);
  int*    deg  = (int*)alloc(N_NODES * 4);
  float*  dinv = (float*)alloc(N_NODES * 4);
  int*    offs = (int*)alloc((N_NODES + 1) * 4);
  int*    curs = (int*)alloc(N_NODES * 4);
  int*    csr  = (int*)alloc(NE * 4);
  unsigned char* spk = (unsigned char*)alloc((size_t)N_NODES * C_IN);
  unsigned short* WTb = (unsigned short*)alloc(2048 * 8 * 2);

  hipMemsetAsync(deg, 0, N_NODES * 4, stream);

  stats_deg_wtb_kernel<<<NB_DEG + NB_STATS + 8, 256, 0, stream>>>(x, dsum, dsq, ei, deg, W0, W1, WTb);
  finalize_scan_kernel<<<129, 256, 0, stream>>>(dsum, dsq, gamma, beta, adbl, bdbl,
                                                deg, offs, curs, dinv);
  lif_fill_kernel<<<NB_LIF + NB_DEG, 256, 0, stream>>>(x, adbl, bdbl, spk, ei, curs, csr);
  main_kernel<<<N_NODES / NPB, 512, 0, stream>>>(spk, offs, csr, dinv, WTb, bias, out);
}

// Round 5
// 230.034 us; speedup vs baseline: 1.1544x; 1.1544x over previous
//
#include <hip/hip_runtime.h>
#include <stdint.h>
#include <math.h>

#define N_NODES 20000
#define C_IN 128
#define C_OUT 64
#define T_STEPS 8
#define NE 160000
#define NB_STATS 1024
#define NB_DEG ((NE + 255) / 256)   // 625
#define NB_LIF ((N_NODES * C_IN) / 256)  // 10000
#define NPB 8        // nodes per block in main kernel
#define RPAD 264     // Bls row stride (bf16 units): 256 + 8 pad

typedef __attribute__((ext_vector_type(8))) short short8;
typedef __attribute__((ext_vector_type(4))) float f32x4;

static __device__ __forceinline__ unsigned short bf16_rne(float f) {
  unsigned u = __builtin_bit_cast(unsigned, f);
  return (unsigned short)((u + 0x7FFFu + ((u >> 16) & 1u)) >> 16);
}

// ---------------- K1: deg atomics + per-channel partial sums (fp64) + WTb build ----------------
// WTb layout: [(mt*8+kt)*64 + lane] * 8 bf16 ; A[m][k], m=mt*16+(lane&15), k=kt*32+(lane>>4)*8+j
__global__ __launch_bounds__(256) void stats_deg_wtb_kernel(const float* __restrict__ x,
                                                            double* __restrict__ dsum,
                                                            double* __restrict__ dsq,
                                                            const int* __restrict__ ei,
                                                            int* __restrict__ deg,
                                                            const float* __restrict__ W0,
                                                            const float* __restrict__ W1,
                                                            unsigned short* __restrict__ WTb) {
  int tid = threadIdx.x;
  if (blockIdx.x < NB_DEG) {                       // degree count (latency-bound, drains early)
    int e = blockIdx.x * 256 + tid;
    if (e < NE) atomicAdd(&deg[ei[NE + e]], 1);
    return;
  }
  if (blockIdx.x >= NB_DEG + NB_STATS) {           // WTb build (8 blocks)
    int idx = (blockIdx.x - NB_DEG - NB_STATS) * 256 + tid;  // 2048 threads
    int mt = idx >> 9, kt = (idx >> 6) & 7, lane = idx & 63;
    int m = mt * 16 + (lane & 15);
    int kb = kt * 32 + (lane >> 4) * 8;
    unsigned short frag[8];
#pragma unroll
    for (int j = 0; j < 8; ++j) {
      int k = kb + j;
      float wv = (k < 128) ? W0[m * 128 + k] : W1[m * 128 + (k - 128)];
      frag[j] = bf16_rne(wv);
    }
    *(uint4*)&WTb[(size_t)idx * 8] = *(uint4*)frag;
    return;
  }
  // stats partials
  int sb = blockIdx.x - NB_DEG;
  const int P = N_NODES * C_IN;
  int gid = sb * 256 + tid;
  double s = 0.0, q = 0.0;
  for (int p = gid; p < P; p += 256 * NB_STATS) {  // stride % 128 == 0 -> c constant per thread
    const float4* xp = (const float4*)(x + (size_t)p * 8);
    float4 a = xp[0], b = xp[1];
    float v[8] = {a.x, a.y, a.z, a.w, b.x, b.y, b.z, b.w};
#pragma unroll
    for (int j = 0; j < 8; ++j) { double d = (double)v[j]; s += d; q += d * d; }
  }
  __shared__ double ls[256], lq[256];
  ls[tid] = s; lq[tid] = q;
  __syncthreads();
  if (tid < 128) {  // tid and tid+128 share channel c==tid
    dsum[tid * NB_STATS + sb] = ls[tid] + ls[tid + 128];
    dsq [tid * NB_STATS + sb] = lq[tid] + lq[tid + 128];
  }
}

// ---------------- K2: finalize per-channel scale/shift + CSR scan + dinv (fused, 1024 thr) ----------------
__global__ __launch_bounds__(1024) void finalize_scan_kernel(const double* __restrict__ dsum,
                                                             const double* __restrict__ dsq,
                                                             const float* __restrict__ gamma,
                                                             const float* __restrict__ beta,
                                                             double* __restrict__ adbl,
                                                             double* __restrict__ bdbl,
                                                             const int* __restrict__ deg,
                                                             int* __restrict__ offs,
                                                             int* __restrict__ cursor,
                                                             float* __restrict__ dinv) {
  int tid = threadIdx.x, lane = tid & 63, w = tid >> 6;
  if (blockIdx.x == 128) {
    // ---- scan block: 1000 active threads x 20 nodes, single pass, registers ----
    __shared__ int wsum[16];
    int base = tid * 20;
    int v[20];
    int s = 0;
    if (tid < 1000) {   // 1000*20 == 20000 exactly; int4 loads are 16B-aligned (80B/thread)
      const int4* dp = (const int4*)(deg + base);
      int4 a0 = dp[0], a1 = dp[1], a2 = dp[2], a3 = dp[3], a4 = dp[4];
      v[0] = a0.x; v[1] = a0.y; v[2] = a0.z; v[3] = a0.w;
      v[4] = a1.x; v[5] = a1.y; v[6] = a1.z; v[7] = a1.w;
      v[8] = a2.x; v[9] = a2.y; v[10] = a2.z; v[11] = a2.w;
      v[12] = a3.x; v[13] = a3.y; v[14] = a3.z; v[15] = a3.w;
      v[16] = a4.x; v[17] = a4.y; v[18] = a4.z; v[19] = a4.w;
#pragma unroll
      for (int j = 0; j < 20; ++j) s += v[j];
    } else {
#pragma unroll
      for (int j = 0; j < 20; ++j) v[j] = 0;
    }
    int p = s;
#pragma unroll
    for (int o = 1; o < 64; o <<= 1) {
      int u = __shfl_up(p, o);
      if (lane >= o) p += u;
    }
    if (lane == 63) wsum[w] = p;
    __syncthreads();
    int wpre = 0;
    for (int j = 0; j < w; ++j) wpre += wsum[j];
    int run = wpre + p - s;
    if (tid < 1000) {
#pragma unroll
      for (int i = 0; i < 20; ++i) {
        int n = base + i;
        offs[n] = run; cursor[n] = run;
        dinv[n] = v[i] > 0 ? (float)(1.0 / sqrt((double)v[i])) : 0.f;
        run += v[i];
      }
    }
    if (tid == 0) {
      int tot = 0;
#pragma unroll
      for (int j = 0; j < 16; ++j) tot += wsum[j];
      offs[N_NODES] = tot;
    }
    return;
  }
  // ---- finalize block: channel c, one partial per thread + shuffle reduce ----
  __shared__ double sred[16], qred[16];
  int c = blockIdx.x;
  double s = dsum[c * NB_STATS + tid];
  double q = dsq [c * NB_STATS + tid];
#pragma unroll
  for (int o = 32; o > 0; o >>= 1) {
    s += __shfl_down(s, o);
    q += __shfl_down(q, o);
  }
  if (lane == 0) { sred[w] = s; qred[w] = q; }
  __syncthreads();
  if (tid == 0) {
    double S = 0.0, Q = 0.0;
#pragma unroll
    for (int j = 0; j < 16; ++j) { S += sred[j]; Q += qred[j]; }
    const double cnt = (double)N_NODES * T_STEPS;
    double mean = S / cnt;
    double var  = Q / cnt - mean * mean;
    double ai = (double)gamma[c] / sqrt(var + 1e-5);
    adbl[c] = ai;
    bdbl[c] = (double)beta[c] - mean * ai;
  }
}

// ---------------- K3: LIF recurrence (fp64) + bit-pack spikes + CSR fill (fused) ----------------
__global__ __launch_bounds__(256) void lif_fill_kernel(const float* __restrict__ x,
                                                       const double* __restrict__ adbl,
                                                       const double* __restrict__ bdbl,
                                                       unsigned char* __restrict__ spk,
                                                       const int* __restrict__ ei,
                                                       int* __restrict__ cursor,
                                                       int* __restrict__ csr) {
  int tid = threadIdx.x;
  if (blockIdx.x >= NB_LIF) {   // CSR fill: hides under lif's HBM phase
    int e = (blockIdx.x - NB_LIF) * 256 + tid;
    if (e < NE) {
      int pos = atomicAdd(&cursor[ei[NE + e]], 1);
      csr[pos] = ei[e];
    }
    return;
  }
  int p = blockIdx.x * 256 + tid;  // exactly N*C threads
  int c = p & (C_IN - 1);
  const float4* xp = (const float4*)(x + (size_t)p * 8);
  float4 a4 = xp[0], b4 = xp[1];
  float v[8] = {a4.x, a4.y, a4.z, a4.w, b4.x, b4.y, b4.z, b4.w};
  double a = adbl[c], bb = bdbl[c];
  double mem = 0.0, sp = 0.0;
  unsigned byte = 0;
#pragma unroll
  for (int t = 0; t < 8; ++t) {
    double h = a * (double)v[t] + bb;
    mem = mem * (0.2 * (1.0 - sp)) + h;
    int fire = mem > 0.5;
    sp = fire ? 1.0 : 0.0;
    byte |= (unsigned)fire << t;
  }
  spk[p] = (unsigned char)byte;
}

// ---------------- K4: fused spike expand + edge aggregate + MFMA GEMM + bias ----------------
// 512 threads = 8 waves; 8 nodes/block, 1 node per wave in Phase B.
__global__ __launch_bounds__(512) void main_kernel(const unsigned char* __restrict__ spk,
                                                   const int* __restrict__ offs,
                                                   const int* __restrict__ csr,
                                                   const float* __restrict__ dinv,
                                                   const unsigned short* __restrict__ WTb,
                                                   const float* __restrict__ bias,
                                                   float* __restrict__ out) {
  __shared__ unsigned short Bls[64 * RPAD];  // [col][k] bf16, col=nl*8+t, k=0..255
  int tid = threadIdx.x;
  int n0 = blockIdx.x * NPB;
  int lane = tid & 63, w = tid >> 6;

  // Phase A: expand own spikes into k in [0,128). 512 tasks = 64 cols x 8 channel-groups.
  {
    int col = tid & 63, cg = tid >> 6;
    int node = n0 + (col >> 3), t = col & 7;
    uint4 u = *(const uint4*)(spk + (size_t)node * 128 + cg * 16);
    unsigned ua[4] = {u.x, u.y, u.z, u.w};
    unsigned ow[8];
#pragma unroll
    for (int i = 0; i < 4; ++i) {
      unsigned vv = (ua[i] >> t) & 0x01010101u;
      unsigned s0 = (vv & 1u)         ? 0x3F80u : 0u;
      unsigned s1 = ((vv >> 8) & 1u)  ? 0x3F800000u : 0u;
      unsigned s2 = ((vv >> 16) & 1u) ? 0x3F80u : 0u;
      unsigned s3 = (vv >> 24)        ? 0x3F800000u : 0u;
      ow[i * 2]     = s0 | s1;
      ow[i * 2 + 1] = s2 | s3;
    }
    uint4 o0 = {ow[0], ow[1], ow[2], ow[3]};
    uint4 o1 = {ow[4], ow[5], ow[6], ow[7]};
    *(uint4*)&Bls[col * RPAD + cg * 16]     = o0;
    *(uint4*)&Bls[col * RPAD + cg * 16 + 8] = o1;
  }

  // Phase B: wave w aggregates node n0+w; lane covers channels 2*lane, 2*lane+1.
  {
    int node = n0 + w;
    int e0 = offs[node], e1 = offs[node + 1];
    const unsigned short* sp16 = (const unsigned short*)spk;
    float acc[16];
#pragma unroll
    for (int j = 0; j < 16; ++j) acc[j] = 0.f;
    int e = e0;
#pragma unroll 1
    for (; e + 4 <= e1; e += 4) {  // 4 edges in flight -> latency chain /4
      int s0 = csr[e], s1 = csr[e + 1], s2 = csr[e + 2], s3 = csr[e + 3];
      float w0 = dinv[s0], w1 = dinv[s1], w2 = dinv[s2], w3 = dinv[s3];
      unsigned b0 = sp16[(size_t)s0 * 64 + lane];
      unsigned b1 = sp16[(size_t)s1 * 64 + lane];
      unsigned b2 = sp16[(size_t)s2 * 64 + lane];
      unsigned b3 = sp16[(size_t)s3 * 64 + lane];
#pragma unroll
      for (int j = 0; j < 16; ++j) {
        acc[j] = fmaf((float)((b0 >> j) & 1u), w0, acc[j]);
        acc[j] = fmaf((float)((b1 >> j) & 1u), w1, acc[j]);
        acc[j] = fmaf((float)((b2 >> j) & 1u), w2, acc[j]);
        acc[j] = fmaf((float)((b3 >> j) & 1u), w3, acc[j]);
      }
    }
#pragma unroll 1
    for (; e < e1; ++e) {
      int src = csr[e];
      float wt = dinv[src];
      unsigned bits = sp16[(size_t)src * 64 + lane];
#pragma unroll
      for (int j = 0; j < 16; ++j)
        acc[j] = fmaf((float)((bits >> j) & 1u), wt, acc[j]);
    }
    float sc = dinv[node];
    int colb = w * 8;
    int c0 = 2 * lane;
#pragma unroll
    for (int t = 0; t < 8; ++t) {
      unsigned pk = (unsigned)bf16_rne(acc[t] * sc) |
                    ((unsigned)bf16_rne(acc[8 + t] * sc) << 16);
      *(unsigned*)&Bls[(colb + t) * RPAD + 128 + c0] = pk;
    }
  }
  __syncthreads();

  // Phase C: D[m=d][n=col] = sum_k WT[m][k] * B[k][n] via 16x16x32 bf16 MFMA.
  // 16 tiles (mt 0..3 x ct 0..3); wave w does (mt=w&3, ct=w>>2) and (mt=w&3, ct=(w>>2)+2).
  int q = lane >> 4, l16 = lane & 15;
  int mt = w & 3, ct0 = w >> 2, ct1 = ct0 + 2;
  int colA = ct0 * 16 + l16, colB = ct1 * 16 + l16;
  const short8* WT8 = (const short8*)WTb;
  f32x4 acc0 = {0, 0, 0, 0}, acc1 = {0, 0, 0, 0};
#pragma unroll
  for (int kt = 0; kt < 8; ++kt) {
    short8 a = WT8[(mt * 8 + kt) * 64 + lane];
    short8 bA = *(const short8*)&Bls[colA * RPAD + kt * 32 + q * 8];
    short8 bB = *(const short8*)&Bls[colB * RPAD + kt * 32 + q * 8];
    acc0 = __builtin_amdgcn_mfma_f32_16x16x32_bf16(a, bA, acc0, 0, 0, 0);
    acc1 = __builtin_amdgcn_mfma_f32_16x16x32_bf16(a, bB, acc1, 0, 0, 0);
  }

  // Epilogue: C/D layout col=lane&15, row=(lane>>4)*4+reg
  int nodeA = n0 + (colA >> 3), tA = colA & 7;
  int nodeB = n0 + (colB >> 3), tB = colB & 7;
  float* obA = out + (size_t)nodeA * 512 + tA;
  float* obB = out + (size_t)nodeB * 512 + tB;
#pragma unroll
  for (int r = 0; r < 4; ++r) {
    int d = mt * 16 + q * 4 + r;
    float bv = bias[d];
    obA[d * 8] = acc0[r] + bv;
    obB[d * 8] = acc1[r] + bv;
  }
}

extern "C" void kernel_launch(void* const* d_in, const int* in_sizes, int n_in,
                              void* d_out, int out_size, void* d_ws, size_t ws_size,
                              hipStream_t stream) {
  const float* x     = (const float*)d_in[0];
  const int*   ei    = (const int*)d_in[1];
  const float* gamma = (const float*)d_in[2];
  const float* beta  = (const float*)d_in[3];
  const float* W0    = (const float*)d_in[4];
  const float* W1    = (const float*)d_in[5];
  const float* bias  = (const float*)d_in[6];
  float* out = (float*)d_out;

  char* ws = (char*)d_ws;
  size_t off = 0;
  auto alloc = [&](size_t bytes) -> void* {
    void* p = ws + off;
    off = (off + bytes + 255) & ~(size_t)255;
    return p;
  };
  double* dsum = (double*)alloc(128 * NB_STATS * 8);
  double* dsq  = (double*)alloc(128 * NB_STATS * 8);
  double* adbl = (double*)alloc(128 * 8);
  double* bdbl = (double*)alloc(128 * 8);
  int*    deg  = (int*)alloc(N_NODES * 4);
  float*  dinv = (float*)alloc(N_NODES * 4);
  int*    offs = (int*)alloc((N_NODES + 1) * 4);
  int*    curs = (int*)alloc(N_NODES * 4);
  int*    csr  = (int*)alloc(NE * 4);
  unsigned char* spk = (unsigned char*)alloc((size_t)N_NODES * C_IN);
  unsigned short* WTb = (unsigned short*)alloc(2048 * 8 * 2);

  hipMemsetAsync(deg, 0, N_NODES * 4, stream);

  stats_deg_wtb_kernel<<<NB_DEG + NB_STATS + 8, 256, 0, stream>>>(x, dsum, dsq, ei, deg, W0, W1, WTb);
  finalize_scan_kernel<<<129, 1024, 0, stream>>>(dsum, dsq, gamma, beta, adbl, bdbl,
                                                 deg, offs, curs, dinv);
  lif_fill_kernel<<<NB_LIF + NB_DEG, 256, 0, stream>>>(x, adbl, bdbl, spk, ei, curs, csr);
  main_kernel<<<N_NODES / NPB, 512, 0, stream>>>(spk, offs, csr, dinv, WTb, bias, out);
}